// Round 1
// baseline (97.988 us; speedup 1.0000x reference)
//
#include <hip/hip_runtime.h>

#define BQ 32
#define H  128
#define C  512
#define D  128

typedef _Float16 half8v __attribute__((ext_vector_type(8)));
typedef float floatx4 __attribute__((ext_vector_type(4)));

typedef const __attribute__((address_space(1))) unsigned int* gas_u32;
typedef __attribute__((address_space(3))) unsigned int* las_u32;

// async global->LDS, 16 B per lane, dest = wave-uniform base + lane*16
__device__ __forceinline__ void stage16(const void* g, void* l) {
  __builtin_amdgcn_global_load_lds((gas_u32)g, (las_u32)l, 16, 0, 0);
}

// ---------------------------------------------------------------------------
// Kernel 0: Q fp32 -> fp16 fragments for 16x16x32 MFMA B-operand, plus zero
// the loss accumulator (d_out).  UNCHANGED layout:
// Frag index (half8 units): ((b*4 + kb)*2 + sh)*64 + lane
//   elem[n = lane&15][k = kb*32 + (lane>>4)*8 + j],  s = sh*16 + n
// Slab for batch b = frags [8b, 8b+8) = 8 KB contiguous.
// ---------------------------------------------------------------------------
__global__ __launch_bounds__(256) void qprep_kernel(const float* __restrict__ q,
                                                    _Float16* __restrict__ qs,
                                                    float* __restrict__ out) {
  int t = blockIdx.x * 256 + threadIdx.x;     // 0..16383, one half8 frag each
  if (t == 0) out[0] = 0.0f;
  int lane = t & 63;
  int sh   = (t >> 6) & 1;
  int kb   = (t >> 7) & 3;
  int b    = t >> 9;
  int s    = sh * 16 + (lane & 15);
  int h    = kb * 32 + (lane >> 4) * 8;
  const float* src = q + ((b * 32 + s) * H + h);
  float4 v0 = *(const float4*)src;
  float4 v1 = *(const float4*)(src + 4);
  half8v o = { (_Float16)v0.x, (_Float16)v0.y, (_Float16)v0.z, (_Float16)v0.w,
               (_Float16)v1.x, (_Float16)v1.y, (_Float16)v1.z, (_Float16)v1.w };
  *(half8v*)(qs + (size_t)t * 8) = o;
}

// ---------------------------------------------------------------------------
// Kernel 1: grid 256, 512 thr (8 waves).  Block handles c in {2bx, 2bx+1}.
// Wave w: cs = w>>2 (which c), w4 = w&3 with dq = w4&1 (d-half), sh = w4>>1
// (s-half) -- identical per-c role split as the verified r7 kernel.
//
// CHANGE vs r7: Q fragments are no longer re-fetched per wave from L2/L3
// (268 MB/launch at ~6.4 TB/s was the bottleneck).  Each 8 KB per-b slab is
// staged ONCE per block into a 4-slot LDS ring via global_load_lds (each of
// the 8 waves stages frag w), consumed by all 8 waves for 2 c's.
// Pipeline: distance-2 prefetch, counted s_waitcnt vmcnt(2) + raw s_barrier
// (no full vmcnt drain in the loop).  Ring S=4 >= D+2 closes slot-reuse race:
// stage at iter j overwrites slab j-2's slot; barrier(j-1) guarantees all
// waves finished compute(j-2).
// ---------------------------------------------------------------------------
__global__ __launch_bounds__(512, 2) void scores_kernel(const float* __restrict__ pos,
                                                        const _Float16* __restrict__ qs,
                                                        float* __restrict__ scores) {
  const int bx   = blockIdx.x;
  const int tid  = threadIdx.x;
  const int w    = tid >> 6;         // 0..7
  const int lane = tid & 63;
  const int cs   = w >> 2;           // c select within pair
  const int w4   = w & 3;
  const int dq   = w4 & 1;           // d-half
  const int sh   = w4 >> 1;          // s-half
  const int quad = lane >> 4;
  const int nrow = lane & 15;

  __shared__ __align__(16) _Float16 qring[4][8][512];  // 4 slots x 8 frags x 1KB = 32 KB
  __shared__ float pmm[2][BQ][4][16];                  // [cs][b][w4][s_local] 16 KB

  const char* qbytes = (const char*)qs;

  // prime: slabs 0,1 -> slots 0,1 (issue before the P prologue so they fly
  // under the P loads; any compiler vmcnt drain for P only helps correctness)
  stage16(qbytes + ((0 * 8 + w) << 10) + lane * 16, &qring[0][w][0]);
  stage16(qbytes + ((1 * 8 + w) << 10) + lane * 16, &qring[1][w][0]);

  // P_c A-frags: A[m = dq*64 + mt*16 + nrow][k = kb*32 + quad*8 + j]
  const float* pc = pos + (size_t)(2 * bx + cs) * (D * H);
  half8v pa[4][4];                   // 64 VGPRs
#pragma unroll
  for (int kb = 0; kb < 4; ++kb)
#pragma unroll
    for (int mt = 0; mt < 4; ++mt) {
      const float* src = pc + ((dq * 64 + mt * 16 + nrow) * H + kb * 32 + quad * 8);
      float4 v0 = *(const float4*)src;
      float4 v1 = *(const float4*)(src + 4);
      half8v f = { (_Float16)v0.x, (_Float16)v0.y, (_Float16)v0.z, (_Float16)v0.w,
                   (_Float16)v1.x, (_Float16)v1.y, (_Float16)v1.z, (_Float16)v1.w };
      pa[mt][kb] = f;
    }

  floatx4 acc[2][4];                 // double-buffered accumulators
  floatx4 zc = {0.f, 0.f, 0.f, 0.f};

  // C/D: col s_local = lane&15, row d_local = quad*4 + r  [m89/m91] -- unchanged
  auto reduce_store = [&](int b, floatx4 (&a)[4]) {
    float m0 = fmaxf(fmaxf(a[0][0], a[0][1]), fmaxf(a[0][2], a[0][3]));
    float m1 = fmaxf(fmaxf(a[1][0], a[1][1]), fmaxf(a[1][2], a[1][3]));
    float m2 = fmaxf(fmaxf(a[2][0], a[2][1]), fmaxf(a[2][2], a[2][3]));
    float m3 = fmaxf(fmaxf(a[3][0], a[3][1]), fmaxf(a[3][2], a[3][3]));
    float m  = fmaxf(fmaxf(m0, m1), fmaxf(m2, m3));
    m = fmaxf(m, __shfl_xor(m, 16));
    m = fmaxf(m, __shfl_xor(m, 32));
    if (lane < 16) pmm[cs][b][w4][lane] = m;
  };

  // main loop: stage slab b+2, wait slab b (counted), barrier, compute b,
  // reduce b-1.  Fully unrolled: all slot/frag offsets are immediates.
#pragma unroll
  for (int b = 0; b < BQ; ++b) {
    const int cur = b & 1;
    {
      // tail iters restage slab 31 into the dead slot to keep vmcnt uniform
      const int srcs = (b + 2 < BQ) ? (b + 2) : (BQ - 1);
      const int slot = (b + 2) & 3;
      stage16(qbytes + ((srcs * 8 + w) << 10) + lane * 16, &qring[slot][w][0]);
    }
    __builtin_amdgcn_sched_barrier(0);                 // pin issue-before-wait
    asm volatile("s_waitcnt vmcnt(2)" ::: "memory");   // slab b landed (2 newest = b+1,b+2)
    __builtin_amdgcn_s_barrier();                      // raw barrier: no vmcnt(0) drain
    __builtin_amdgcn_sched_barrier(0);                 // no ds_read hoists above barrier

    const int rs = b & 3;
    const half8v q0 = *(const half8v*)&qring[rs][0 + sh][(size_t)lane * 8];
    const half8v q1 = *(const half8v*)&qring[rs][2 + sh][(size_t)lane * 8];
    const half8v q2 = *(const half8v*)&qring[rs][4 + sh][(size_t)lane * 8];
    const half8v q3 = *(const half8v*)&qring[rs][6 + sh][(size_t)lane * 8];
#pragma unroll
    for (int mt = 0; mt < 4; ++mt)
      acc[cur][mt] = __builtin_amdgcn_mfma_f32_16x16x32_f16(pa[mt][0], q0, zc, 0, 0, 0);
#pragma unroll
    for (int mt = 0; mt < 4; ++mt)
      acc[cur][mt] = __builtin_amdgcn_mfma_f32_16x16x32_f16(pa[mt][1], q1, acc[cur][mt], 0, 0, 0);
#pragma unroll
    for (int mt = 0; mt < 4; ++mt)
      acc[cur][mt] = __builtin_amdgcn_mfma_f32_16x16x32_f16(pa[mt][2], q2, acc[cur][mt], 0, 0, 0);
#pragma unroll
    for (int mt = 0; mt < 4; ++mt)
      acc[cur][mt] = __builtin_amdgcn_mfma_f32_16x16x32_f16(pa[mt][3], q3, acc[cur][mt], 0, 0, 0);
    if (b > 0) reduce_store(b - 1, acc[cur ^ 1]);
  }
  reduce_store(BQ - 1, acc[1]);      // b=31 landed in acc[1]

  __syncthreads();                   // full drain once; pmm now visible

  // epilogue: scores[b][2bx+cs] = 50 * sum_s max over the two d-half waves
  {
    int cs2 = tid >> 8;
    int r   = tid & 255;
    int b   = r >> 3;
    int t8  = r & 7;
    float v = 0.f;
#pragma unroll
    for (int j = 0; j < 4; ++j) {
      int s  = t8 * 4 + j;
      int h2 = s >> 4, sl = s & 15;
      v += fmaxf(pmm[cs2][b][2 * h2][sl], pmm[cs2][b][2 * h2 + 1][sl]);
    }
    v += __shfl_xor(v, 1);
    v += __shfl_xor(v, 2);
    v += __shfl_xor(v, 4);
    if (t8 == 0) scores[b * C + (2 * bx + cs2)] = v * 50.0f;   // / TEMPERATURE
  }
}

// ---------------------------------------------------------------------------
// Kernel 2: one block per b; loss += (logsumexp_c - scores[b][0]) / 32
// ---------------------------------------------------------------------------
__global__ __launch_bounds__(256) void loss_kernel(const float* __restrict__ scores,
                                                   float* __restrict__ out) {
  __shared__ float red[8];
  const int b = blockIdx.x, tid = threadIdx.x, w = tid >> 6, lane = tid & 63;
  const float* row = scores + b * C;
  float x0 = row[tid], x1 = row[tid + 256];
  float mx = fmaxf(x0, x1);
#pragma unroll
  for (int off = 1; off < 64; off <<= 1) mx = fmaxf(mx, __shfl_xor(mx, off));
  if (lane == 0) red[w] = mx;
  __syncthreads();
  float bmax = fmaxf(fmaxf(red[0], red[1]), fmaxf(red[2], red[3]));
  float e = __expf(x0 - bmax) + __expf(x1 - bmax);
#pragma unroll
  for (int off = 1; off < 64; off <<= 1) e += __shfl_xor(e, off);
  if (lane == 0) red[4 + w] = e;
  __syncthreads();
  if (tid == 0) {
    float s = red[4] + red[5] + red[6] + red[7];
    atomicAdd(out, (bmax + __logf(s) - row[0]) * (1.0f / 32.0f));
  }
}

extern "C" void kernel_launch(void* const* d_in, const int* in_sizes, int n_in,
                              void* d_out, int out_size, void* d_ws, size_t ws_size,
                              hipStream_t stream) {
  const float* q = (const float*)d_in[0];   // [32,32,128] fp32
  const float* p = (const float*)d_in[1];   // [512,128,128] fp32
  float* scores  = (float*)d_ws;                              // 64 KB
  _Float16* qs   = (_Float16*)((char*)d_ws + 65536);          // 256 KB fp16 frags

  qprep_kernel<<<64, 256, 0, stream>>>(q, qs, (float*)d_out);
  scores_kernel<<<256, 512, 0, stream>>>(p, qs, scores);
  loss_kernel<<<32, 256, 0, stream>>>(scores, (float*)d_out);
}